// Round 11
// baseline (9306.740 us; speedup 1.0000x reference)
//
#include <hip/hip_runtime.h>
#include <stdint.h>

typedef __bf16 bf16;
typedef __attribute__((ext_vector_type(8))) __bf16 bf16x8;
typedef __attribute__((ext_vector_type(4))) float f32x4;

#define GRU_H 2048
#define ODIM 96
#define PADX 128
#define BATCH 1024
#define TSTEPS 25

__device__ __forceinline__ float sigm(float x) { return 1.f / (1.f + __expf(-x)); }

__device__ __forceinline__ void gload16(const void* g, void* l) {
  __builtin_amdgcn_global_load_lds((const __attribute__((address_space(1))) uint32_t*)g,
                                   (__attribute__((address_space(3))) uint32_t*)l, 16, 0, 0);
}

// ---------------- init / convert kernels ----------------
__global__ void k_cvt(const float* __restrict__ s, bf16* __restrict__ d, int n) {
  int stride = gridDim.x * blockDim.x;
  for (int i = blockIdx.x * blockDim.x + threadIdx.x; i < n; i += stride)
    d[i] = (bf16)s[i];
}

__global__ void k_cvt_pad(const float* __restrict__ s, bf16* __restrict__ d,
                          int rows, int cin, int cout) {
  int n = rows * cout;
  int stride = gridDim.x * blockDim.x;
  for (int i = blockIdx.x * blockDim.x + threadIdx.x; i < n; i += stride) {
    int r = i / cout, c = i - r * cout;
    d[i] = (c < cin) ? (bf16)s[r * cin + c] : (bf16)0.f;
  }
}

__global__ void k_init_h(const float* __restrict__ s, float* __restrict__ hf,
                         bf16* __restrict__ hb, int n) {
  int stride = gridDim.x * blockDim.x;
  for (int i = blockIdx.x * blockDim.x + threadIdx.x; i < n; i += stride) {
    float v = s[i];
    hf[i] = v;
    hb[i] = (bf16)v;
  }
}

// ---------------- fused GRU layer kernel ----------------
// R4 skeleton (8 waves, 128r x 64c x 3g tile, grid (32,8)=1 block/CU, stage via
// global_load_lds w/ source-side XOR swizzle) + REGISTER READ-AHEAD, spill-safe:
//  - 4 LDS buffers x 40KB = 160KB (exactly the CU pool).
//  - body(s): vmcnt(5) [drains stage(s+1), issued 2 bodies (~2us) ago -> free];
//    barrier; stage(s+3); READF buf(s+1)->Rnext (14 ds_read_b128);
//    sched_barrier; setprio(1); 24 MFMA on Rcur; setprio(0).
//  - All fragment arrays accessed ONLY with literal indices through macros.
//  - __launch_bounds__(512, 1): the HIP compiler treats arg2 as min BLOCKS/CU
//    (CUDA semantics) -> arg2=2 caps VGPR at 128 and spills ~90 regs (R9/R10's
//    376MB WRITE_SIZE failure). arg2=1 -> cap 256; budget ~220 fits, still
//    2 waves/SIMD from the 8-wave block at 1 block/CU.
// Templated on KX so S is constexpr (S=64 or 34; x4-unrolled loop + 2-body peel).

#define LD8(bp, o) (*(const bf16x8*)((bp) + (o)))
#define MF(a, b, c) c = __builtin_amdgcn_mfma_f32_16x16x32_bf16(a, b, c, 0, 0, 0)

#define READF(bp, R) do {                                                     \
  R[0] = LD8(bp, offR[0]);  R[1] = LD8(bp, offR[1]);                          \
  R[2] = LD8(bp, offR[2]);  R[3] = LD8(bp, offR[3]);                          \
  R[8] = LD8(bp, offR[8]);  R[9] = LD8(bp, offR[9]);  R[10] = LD8(bp, offR[10]);\
  R[4] = LD8(bp, offR[4]);  R[5] = LD8(bp, offR[5]);                          \
  R[6] = LD8(bp, offR[6]);  R[7] = LD8(bp, offR[7]);                          \
  R[11] = LD8(bp, offR[11]); R[12] = LD8(bp, offR[12]); R[13] = LD8(bp, offR[13]);\
} while (0)

#define MFMA24(R, accN) do {                                                  \
  MF(R[0], R[8], accR[0]);  MF(R[1], R[8], accR[1]);                          \
  MF(R[2], R[8], accR[2]);  MF(R[3], R[8], accR[3]);                          \
  MF(R[0], R[9], accZ[0]);  MF(R[1], R[9], accZ[1]);                          \
  MF(R[2], R[9], accZ[2]);  MF(R[3], R[9], accZ[3]);                          \
  MF(R[0], R[10], accN[0]); MF(R[1], R[10], accN[1]);                         \
  MF(R[2], R[10], accN[2]); MF(R[3], R[10], accN[3]);                         \
  MF(R[4], R[11], accR[0]); MF(R[5], R[11], accR[1]);                         \
  MF(R[6], R[11], accR[2]); MF(R[7], R[11], accR[3]);                         \
  MF(R[4], R[12], accZ[0]); MF(R[5], R[12], accZ[1]);                         \
  MF(R[6], R[12], accZ[2]); MF(R[7], R[12], accZ[3]);                         \
  MF(R[4], R[13], accN[0]); MF(R[5], R[13], accN[1]);                         \
  MF(R[6], R[13], accN[2]); MF(R[7], R[13], accN[3]);                         \
} while (0)

#define BODY(s, bn_, bw_, Rc, Rn) do {                                        \
  if ((s) + 2 < S) asm volatile("s_waitcnt vmcnt(5)" ::: "memory");           \
  else             asm volatile("s_waitcnt vmcnt(0)" ::: "memory");           \
  __builtin_amdgcn_s_barrier();                                               \
  if ((s) + 3 < S) stageSel((s) + 3, bw_);                                    \
  if ((s) + 1 < S) { READF(bn_, Rn); }                                        \
  __builtin_amdgcn_sched_barrier(0);                                          \
  __builtin_amdgcn_s_setprio(1);                                              \
  if ((s) < S1) { MFMA24(Rc, accNH); } else { MFMA24(Rc, accNI); }            \
  __builtin_amdgcn_s_setprio(0);                                              \
} while (0)

template <int KX>
__global__ __launch_bounds__(512, 1) void k_gru(
    const bf16* __restrict__ xb,                  // x input [1024][KX]
    const bf16* __restrict__ hb,                  // h_prev bf16 [1024][2048]
    const bf16* __restrict__ wih,                 // [3*2048][KX]
    const bf16* __restrict__ whh,                 // [3*2048][2048]
    const float* __restrict__ bih, const float* __restrict__ bhh,
    const float* __restrict__ hprevf,             // h_prev fp32 master
    float* __restrict__ hnewf, bf16* __restrict__ hnewb) {
  __shared__ alignas(16) char sm[4][40960];       // per buffer: A 16KB + B 24KB

  constexpr int S1 = GRU_H / 64;                  // 32 hh steps
  constexpr int S2 = KX / 64;                     // 2 or 32 ih steps
  constexpr int S = S1 + S2;                      // 34 or 64
  constexpr int M4 = (S / 4) * 4;                 // 32 or 64

  const int tid = threadIdx.x;
  const int l = tid & 63;
  const int w = tid >> 6;
  const int wm = w & 1, wn = w >> 1;
  const int wb = tid & ~63;
  const int bn0 = blockIdx.x * 64;
  const int bm0 = blockIdx.y * 128;
  const int lm = l >> 4, ln = l & 15;
  char* const b0 = &sm[0][0];
  char* const b1 = &sm[1][0];
  char* const b2 = &sm[2][0];
  char* const b3 = &sm[3][0];

  f32x4 accR[4] = {};
  f32x4 accZ[4] = {};
  f32x4 accNH[4] = {};
  f32x4 accNI[4] = {};

  // staging bases (source-side XOR swizzle; slot it-invariant, rows step 64)
  const bf16* pAhh[2]; const bf16* pAih[2]; int ldsA[2];
  const bf16* pWhh[3]; const bf16* pWih[3]; int ldsB[3];
#pragma unroll
  for (int i = 0; i < 2; ++i) {
    int c = i * 512 + tid, row = c >> 3, slot = (c & 7) ^ (row & 7);
    pAhh[i] = hb + (size_t)(bm0 + row) * GRU_H + slot * 8;
    pAih[i] = xb + (size_t)(bm0 + row) * KX + slot * 8;
    ldsA[i] = (i * 512 + wb) << 4;
  }
#pragma unroll
  for (int i = 0; i < 3; ++i) {
    int c = i * 512 + tid, row = c >> 3, slot = (c & 7) ^ (row & 7);
    int g = row >> 6, r = row & 63;
    pWhh[i] = whh + (size_t)(g * GRU_H + bn0 + r) * GRU_H + slot * 8;
    pWih[i] = wih + (size_t)(g * GRU_H + bn0 + r) * KX + slot * 8;
    ldsB[i] = 16384 + ((i * 512 + wb) << 4);
  }

  auto stageSel = [&](int sp, char* sb) {
    if (sp < S1) {
      int koff = sp * 64;
#pragma unroll
      for (int i = 0; i < 2; ++i) gload16(pAhh[i] + koff, sb + ldsA[i]);
#pragma unroll
      for (int i = 0; i < 3; ++i) gload16(pWhh[i] + koff, sb + ldsB[i]);
    } else {
      int koff = (sp - S1) * 64;
#pragma unroll
      for (int i = 0; i < 2; ++i) gload16(pAih[i] + koff, sb + ldsA[i]);
#pragma unroll
      for (int i = 0; i < 3; ++i) gload16(pWih[i] + koff, sb + ldsB[i]);
    }
  };

  // precomputed byte offsets within a buffer for the 14 fragment reads
  int offR[14];
#pragma unroll
  for (int kf = 0; kf < 2; ++kf) {
    const int pos = ((kf * 4 + lm) ^ (ln & 7)) << 4;
#pragma unroll
    for (int mf = 0; mf < 4; ++mf)
      offR[kf * 4 + mf] = (wm * 64 + mf * 16 + ln) * 128 + pos;
#pragma unroll
    for (int g = 0; g < 3; ++g)
      offR[8 + kf * 3 + g] = 16384 + (g * 64 + wn * 16 + ln) * 128 + pos;
  }

  bf16x8 RA[14], RB[14];

  // prologue: stage 3 deep, read frags of step 0
  stageSel(0, b0);
  stageSel(1, b1);
  stageSel(2, b2);
  asm volatile("s_waitcnt vmcnt(10)" ::: "memory");   // stage(0) drained
  __builtin_amdgcn_s_barrier();
  READF(b0, RA);

  for (int s = 0; s < M4; s += 4) {
    BODY(s + 0, b1, b3, RA, RB);
    BODY(s + 1, b2, b0, RB, RA);
    BODY(s + 2, b3, b1, RA, RB);
    BODY(s + 3, b0, b2, RB, RA);
  }
  if constexpr (S % 4 == 2) {                        // S=34 peel: bodies 32,33
    BODY(S - 2, b1, b3, RA, RB);
    BODY(S - 1, b2, b0, RB, RA);
  }

  // ---- GRU epilogue ----
  {
    int j = bn0 + wn * 16 + ln;
    float br = bih[j] + bhh[j];
    float bz = bih[GRU_H + j] + bhh[GRU_H + j];
    float bin = bih[2 * GRU_H + j];
    float bhn = bhh[2 * GRU_H + j];
#pragma unroll
    for (int mf = 0; mf < 4; ++mf) {
#pragma unroll
      for (int rr = 0; rr < 4; ++rr) {
        int m = bm0 + wm * 64 + mf * 16 + lm * 4 + rr;
        size_t idx = (size_t)m * GRU_H + j;
        float hp = hprevf[idx];
        float rg = sigm(accR[mf][rr] + br);
        float zg = sigm(accZ[mf][rr] + bz);
        float ng = tanhf(accNI[mf][rr] + bin + rg * (accNH[mf][rr] + bhn));
        float hn = (1.f - zg) * ng + zg * hp;
        hnewf[idx] = hn;
        hnewb[idx] = (bf16)hn;
      }
    }
  }
}

// ---------------- FC (split-K) ----------------
__global__ __launch_bounds__(256, 1) void k_fc_part(const bf16* __restrict__ h1b,
                                                    const bf16* __restrict__ wfc,
                                                    float* __restrict__ part) {
  const int kc = blockIdx.x;
  const int mt = blockIdx.y;
  const int l = threadIdx.x & 63, w = threadIdx.x >> 6;
  const int lm = l >> 4, ln = l & 15;
  const int m0 = mt * 64 + w * 16;
  const int k0 = kc * 128;
  f32x4 acc[6] = {};
#pragma unroll
  for (int kf = 0; kf < 4; ++kf) {
    bf16x8 a = *(const bf16x8*)&h1b[(size_t)(m0 + ln) * GRU_H + k0 + kf * 32 + lm * 8];
#pragma unroll
    for (int nf = 0; nf < 6; ++nf) {
      bf16x8 b = *(const bf16x8*)&wfc[(size_t)(nf * 16 + ln) * GRU_H + k0 + kf * 32 + lm * 8];
      acc[nf] = __builtin_amdgcn_mfma_f32_16x16x32_bf16(a, b, acc[nf], 0, 0, 0);
    }
  }
  float* base = part + (size_t)kc * (BATCH * ODIM);
#pragma unroll
  for (int nf = 0; nf < 6; ++nf)
#pragma unroll
    for (int rr = 0; rr < 4; ++rr)
      base[(size_t)(m0 + lm * 4 + rr) * ODIM + nf * 16 + ln] = acc[nf][rr];
}

__global__ void k_fc_red(const float* __restrict__ part, const float* __restrict__ bfc,
                         float* __restrict__ dout, bf16* __restrict__ decb, int t) {
  int i = blockIdx.x * blockDim.x + threadIdx.x;
  if (i >= BATCH * ODIM) return;
  int m = i / ODIM, n = i - m * ODIM;
  float s = bfc[n];
#pragma unroll
  for (int kc = 0; kc < 16; ++kc) s += part[(size_t)kc * (BATCH * ODIM) + i];
  s = sigm(s);
  dout[(size_t)m * (TSTEPS * ODIM) + t * ODIM + n] = s;
  decb[m * PADX + n] = (bf16)s;
}

// ---------------- launch ----------------
extern "C" void kernel_launch(void* const* d_in, const int* in_sizes, int n_in,
                              void* d_out, int out_size, void* d_ws, size_t ws_size,
                              hipStream_t stream) {
  const float* input   = (const float*)d_in[0];
  const float* hiddens = (const float*)d_in[2];
  const float* W_ih0   = (const float*)d_in[3];
  const float* W_hh0   = (const float*)d_in[4];
  const float* b_ih0   = (const float*)d_in[5];
  const float* b_hh0   = (const float*)d_in[6];
  const float* W_ih1   = (const float*)d_in[7];
  const float* W_hh1   = (const float*)d_in[8];
  const float* b_ih1   = (const float*)d_in[9];
  const float* b_hh1   = (const float*)d_in[10];
  const float* W_fc    = (const float*)d_in[11];
  const float* b_fc    = (const float*)d_in[12];
  float* out = (float*)d_out;

  char* p = (char*)d_ws;
  auto take = [&](size_t n) { char* q = p; p += (n + 255) & ~(size_t)255; return q; };
  bf16* wih0b = (bf16*)take((size_t)3 * GRU_H * PADX * 2);
  bf16* whh0b = (bf16*)take((size_t)3 * GRU_H * GRU_H * 2);
  bf16* wih1b = (bf16*)take((size_t)3 * GRU_H * GRU_H * 2);
  bf16* whh1b = (bf16*)take((size_t)3 * GRU_H * GRU_H * 2);
  bf16* wfcb  = (bf16*)take((size_t)ODIM * GRU_H * 2);
  bf16* decb  = (bf16*)take((size_t)BATCH * PADX * 2);
  float* h0f[2], *h1f[2];
  bf16* h0b[2], *h1b[2];
  h0f[0] = (float*)take((size_t)BATCH * GRU_H * 4);
  h0f[1] = (float*)take((size_t)BATCH * GRU_H * 4);
  h1f[0] = (float*)take((size_t)BATCH * GRU_H * 4);
  h1f[1] = (float*)take((size_t)BATCH * GRU_H * 4);
  h0b[0] = (bf16*)take((size_t)BATCH * GRU_H * 2);
  h0b[1] = (bf16*)take((size_t)BATCH * GRU_H * 2);
  h1b[0] = (bf16*)take((size_t)BATCH * GRU_H * 2);
  h1b[1] = (bf16*)take((size_t)BATCH * GRU_H * 2);
  float* fcpart = (float*)take((size_t)16 * BATCH * ODIM * 4);

  // one-time (per launch) conversions
  k_cvt_pad<<<768, 256, 0, stream>>>(W_ih0, wih0b, 3 * GRU_H, ODIM, PADX);
  k_cvt<<<2048, 256, 0, stream>>>(W_hh0, whh0b, 3 * GRU_H * GRU_H);
  k_cvt<<<2048, 256, 0, stream>>>(W_ih1, wih1b, 3 * GRU_H * GRU_H);
  k_cvt<<<2048, 256, 0, stream>>>(W_hh1, whh1b, 3 * GRU_H * GRU_H);
  k_cvt<<<192, 256, 0, stream>>>(W_fc, wfcb, ODIM * GRU_H);
  k_cvt_pad<<<512, 256, 0, stream>>>(input, decb, BATCH, ODIM, PADX);
  k_init_h<<<2048, 256, 0, stream>>>(hiddens, h0f[0], h0b[0], BATCH * GRU_H);
  k_init_h<<<2048, 256, 0, stream>>>(hiddens + (size_t)BATCH * GRU_H, h1f[0], h1b[0], BATCH * GRU_H);

  int cur = 0;
  for (int t = 0; t < TSTEPS; ++t) {
    int nxt = cur ^ 1;
    k_gru<PADX><<<dim3(32, 8), 512, 0, stream>>>(decb, h0b[cur], wih0b, whh0b,
                                                 b_ih0, b_hh0, h0f[cur], h0f[nxt], h0b[nxt]);
    k_gru<GRU_H><<<dim3(32, 8), 512, 0, stream>>>(h0b[nxt], h1b[cur], wih1b, whh1b,
                                                  b_ih1, b_hh1, h1f[cur], h1f[nxt], h1b[nxt]);
    k_fc_part<<<dim3(16, 16), 256, 0, stream>>>(h1b[nxt], wfcb, fcpart);
    k_fc_red<<<384, 256, 0, stream>>>(fcpart, b_fc, out, decb, t);
    cur = nxt;
  }
}

// Round 12
// 3672.935 us; speedup vs baseline: 2.5339x; 2.5339x over previous
//
#include <hip/hip_runtime.h>
#include <stdint.h>

typedef __bf16 bf16;
typedef __attribute__((ext_vector_type(8))) __bf16 bf16x8;
typedef __attribute__((ext_vector_type(4))) float f32x4;

#define GRU_H 2048
#define ODIM 96
#define PADX 128
#define BATCH 1024
#define TSTEPS 25

__device__ __forceinline__ float sigm(float x) { return 1.f / (1.f + __expf(-x)); }

__device__ __forceinline__ void gload16(const void* g, void* l) {
  __builtin_amdgcn_global_load_lds((const __attribute__((address_space(1))) uint32_t*)g,
                                   (__attribute__((address_space(3))) uint32_t*)l, 16, 0, 0);
}

// ---------------- init / convert kernels ----------------
__global__ void k_cvt(const float* __restrict__ s, bf16* __restrict__ d, int n) {
  int stride = gridDim.x * blockDim.x;
  for (int i = blockIdx.x * blockDim.x + threadIdx.x; i < n; i += stride)
    d[i] = (bf16)s[i];
}

__global__ void k_cvt_pad(const float* __restrict__ s, bf16* __restrict__ d,
                          int rows, int cin, int cout) {
  int n = rows * cout;
  int stride = gridDim.x * blockDim.x;
  for (int i = blockIdx.x * blockDim.x + threadIdx.x; i < n; i += stride) {
    int r = i / cout, c = i - r * cout;
    d[i] = (c < cin) ? (bf16)s[r * cin + c] : (bf16)0.f;
  }
}

__global__ void k_init_h(const float* __restrict__ s, float* __restrict__ hf,
                         bf16* __restrict__ hb, int n) {
  int stride = gridDim.x * blockDim.x;
  for (int i = blockIdx.x * blockDim.x + threadIdx.x; i < n; i += stride) {
    float v = s[i];
    hf[i] = v;
    hb[i] = (bf16)v;
  }
}

// ---------------- fused GRU layer kernel ----------------
// 256 thr = 4 waves (wn = w: 16-col slice). Block tile 64 rows x 64 H-cols x
// 3 gates, BK=32. grid (32,16) = 512 blocks = 2 blocks/CU (LDS 48KB/block):
// the two co-resident blocks drift out of phase, so one block's LDS-read burst
// overlaps the other's MFMA cluster (m114 inter-block overlap) — the overlap
// the barrier-locked 1-block/CU config can't get without (spilling) read-ahead.
// 3 x 16KB buffers, depth-2 prefetch, ONE fused {vmcnt(4) lgkmcnt(0); barrier}
// per step (counted: stage(s+1)'s 4 loads stay in flight; never 0 mid-loop).
// BK=32 swizzle: 4 slots of 16B per 64B row; read pos = (lm + (row>>1)) & 3
// (worst 2-way bank alias = free), inverse rotation applied on the GLOBAL
// source address (rule #21: gload_lds writes linearly).
__global__ __launch_bounds__(256) void k_gru(
    const bf16* __restrict__ xb, int kx,          // x input [1024][kx], kx=128 or 2048
    const bf16* __restrict__ hb,                  // h_prev bf16 [1024][2048]
    const bf16* __restrict__ wih,                 // [3*2048][kx]
    const bf16* __restrict__ whh,                 // [3*2048][2048]
    const float* __restrict__ bih, const float* __restrict__ bhh,
    const float* __restrict__ hprevf,             // h_prev fp32 master
    float* __restrict__ hnewf, bf16* __restrict__ hnewb) {
  __shared__ alignas(16) char sm[3][16384];       // per buffer: A 4KB + B 12KB

  const int tid = threadIdx.x;
  const int l = tid & 63;
  const int wn = tid >> 6;                        // 4 waves = 4 col-slices of 16
  const int bn0 = blockIdx.x * 64;
  const int bm0 = blockIdx.y * 64;
  const int lm = l >> 4, ln = l & 15;
  char* const b0 = &sm[0][0];
  char* const b1 = &sm[1][0];
  char* const b2 = &sm[2][0];

  const int S1 = GRU_H / 32;                      // 64 hh steps
  const int S2 = kx / 32;                         // 4 or 64 ih steps
  const int S = S1 + S2;                          // 68 or 128; (S-2) % 3 == 0

  f32x4 accR[4] = {};
  f32x4 accZ[4] = {};
  f32x4 accNH[4] = {};
  f32x4 accNI[4] = {};

  // staging: chunk tid -> row r0 = tid>>2 (64B rows), LDS position p = tid&3.
  // position p holds k-group (p - (r0>>1)) & 3  (inverse of the read rotation).
  const int r0 = tid >> 2;
  const int kg = ((((tid & 3) - (tid >> 3)) & 3)) * 8;   // k element offset
  const bf16* pAhh = hb + (size_t)(bm0 + r0) * GRU_H + kg;
  const bf16* pAih = xb + (size_t)(bm0 + r0) * kx + kg;
  const bf16* pWhh[3]; const bf16* pWih[3]; int ldsB[3];
#pragma unroll
  for (int g = 0; g < 3; ++g) {
    pWhh[g] = whh + (size_t)(g * GRU_H + bn0 + r0) * GRU_H + kg;
    pWih[g] = wih + (size_t)(g * GRU_H + bn0 + r0) * kx + kg;
    ldsB[g] = 4096 + ((g * 256 + (tid & ~63)) << 4);
  }
  const int ldsA = (tid & ~63) << 4;

  auto stageSel = [&](int sp, char* sb) {
    if (sp < S1) {
      int k0 = sp * 32;
      gload16(pAhh + k0, sb + ldsA);
#pragma unroll
      for (int g = 0; g < 3; ++g) gload16(pWhh[g] + k0, sb + ldsB[g]);
    } else {
      int k0 = (sp - S1) * 32;
      gload16(pAih + k0, sb + ldsA);
#pragma unroll
      for (int g = 0; g < 3; ++g) gload16(pWih[g] + k0, sb + ldsB[g]);
    }
  };

  // read pos rotation: row>>1 ≡ (ln>>1) (mod 4) for all frag rows here.
  const int pos = ((lm + (ln >> 1)) & 3) << 4;

  auto computeStep = [&](const char* bp, f32x4 (&accN)[4]) {
    bf16x8 af[4];
#pragma unroll
    for (int mf = 0; mf < 4; ++mf)
      af[mf] = *(const bf16x8*)(bp + (mf * 16 + ln) * 64 + pos);
#pragma unroll
    for (int g = 0; g < 3; ++g) {
      bf16x8 bq = *(const bf16x8*)(bp + 4096 + (g * 64 + wn * 16 + ln) * 64 + pos);
      f32x4* accG = (g == 0) ? accR : (g == 1) ? accZ : accN;
#pragma unroll
      for (int mf = 0; mf < 4; ++mf)
        accG[mf] = __builtin_amdgcn_mfma_f32_16x16x32_bf16(af[mf], bq, accG[mf], 0, 0, 0);
    }
  };

  auto body = [&](int s, char* bufR, char* bufW, bool last) {
    // vmcnt(4): stage(s+1)'s 4 loads may stay in flight; stage(s) is drained.
    // lgkmcnt(0): my ds_reads of the buffer bufW replaces are done (WAR-safe
    // after the barrier, since every wave waits before crossing it).
    if (!last) asm volatile("s_waitcnt vmcnt(4) lgkmcnt(0)" ::: "memory");
    else       asm volatile("s_waitcnt vmcnt(0) lgkmcnt(0)" ::: "memory");
    __builtin_amdgcn_s_barrier();
    if (s + 2 < S) stageSel(s + 2, bufW);
    __builtin_amdgcn_s_setprio(1);
    if (s < S1) computeStep(bufR, accNH);
    else        computeStep(bufR, accNI);
    __builtin_amdgcn_s_setprio(0);
  };

  // prologue: fill 2 deep
  stageSel(0, b0);
  stageSel(1, b1);

  int s = 0;
  for (; s + 2 < S; s += 3) {                     // (S-2)%3==0: exits at s=S-2
    body(s + 0, b0, b2, false);
    body(s + 1, b1, b0, false);
    body(s + 2, b2, b1, false);
  }
  body(s + 0, b0, b2, false);                     // s = S-2 (no stage; vmcnt(4))
  body(s + 1, b1, b0, true);                      // s = S-1 (vmcnt(0))

  // ---- GRU epilogue ----
  {
    int j = bn0 + wn * 16 + ln;
    float br = bih[j] + bhh[j];
    float bz = bih[GRU_H + j] + bhh[GRU_H + j];
    float bin = bih[2 * GRU_H + j];
    float bhn = bhh[2 * GRU_H + j];
#pragma unroll
    for (int mf = 0; mf < 4; ++mf) {
#pragma unroll
      for (int rr = 0; rr < 4; ++rr) {
        int m = bm0 + mf * 16 + lm * 4 + rr;
        size_t idx = (size_t)m * GRU_H + j;
        float hp = hprevf[idx];
        float rg = sigm(accR[mf][rr] + br);
        float zg = sigm(accZ[mf][rr] + bz);
        float ng = tanhf(accNI[mf][rr] + bin + rg * (accNH[mf][rr] + bhn));
        float hn = (1.f - zg) * ng + zg * hp;
        hnewf[idx] = hn;
        hnewb[idx] = (bf16)hn;
      }
    }
  }
}

// ---------------- FC (split-K) ----------------
__global__ __launch_bounds__(256, 1) void k_fc_part(const bf16* __restrict__ h1b,
                                                    const bf16* __restrict__ wfc,
                                                    float* __restrict__ part) {
  const int kc = blockIdx.x;
  const int mt = blockIdx.y;
  const int l = threadIdx.x & 63, w = threadIdx.x >> 6;
  const int lm = l >> 4, ln = l & 15;
  const int m0 = mt * 64 + w * 16;
  const int k0 = kc * 128;
  f32x4 acc[6] = {};
#pragma unroll
  for (int kf = 0; kf < 4; ++kf) {
    bf16x8 a = *(const bf16x8*)&h1b[(size_t)(m0 + ln) * GRU_H + k0 + kf * 32 + lm * 8];
#pragma unroll
    for (int nf = 0; nf < 6; ++nf) {
      bf16x8 b = *(const bf16x8*)&wfc[(size_t)(nf * 16 + ln) * GRU_H + k0 + kf * 32 + lm * 8];
      acc[nf] = __builtin_amdgcn_mfma_f32_16x16x32_bf16(a, b, acc[nf], 0, 0, 0);
    }
  }
  float* base = part + (size_t)kc * (BATCH * ODIM);
#pragma unroll
  for (int nf = 0; nf < 6; ++nf)
#pragma unroll
    for (int rr = 0; rr < 4; ++rr)
      base[(size_t)(m0 + lm * 4 + rr) * ODIM + nf * 16 + ln] = acc[nf][rr];
}

__global__ void k_fc_red(const float* __restrict__ part, const float* __restrict__ bfc,
                         float* __restrict__ dout, bf16* __restrict__ decb, int t) {
  int i = blockIdx.x * blockDim.x + threadIdx.x;
  if (i >= BATCH * ODIM) return;
  int m = i / ODIM, n = i - m * ODIM;
  float s = bfc[n];
#pragma unroll
  for (int kc = 0; kc < 16; ++kc) s += part[(size_t)kc * (BATCH * ODIM) + i];
  s = sigm(s);
  dout[(size_t)m * (TSTEPS * ODIM) + t * ODIM + n] = s;
  decb[m * PADX + n] = (bf16)s;
}

// ---------------- launch ----------------
extern "C" void kernel_launch(void* const* d_in, const int* in_sizes, int n_in,
                              void* d_out, int out_size, void* d_ws, size_t ws_size,
                              hipStream_t stream) {
  const float* input   = (const float*)d_in[0];
  const float* hiddens = (const float*)d_in[2];
  const float* W_ih0   = (const float*)d_in[3];
  const float* W_hh0   = (const float*)d_in[4];
  const float* b_ih0   = (const float*)d_in[5];
  const float* b_hh0   = (const float*)d_in[6];
  const float* W_ih1   = (const float*)d_in[7];
  const float* W_hh1   = (const float*)d_in[8];
  const float* b_ih1   = (const float*)d_in[9];
  const float* b_hh1   = (const float*)d_in[10];
  const float* W_fc    = (const float*)d_in[11];
  const float* b_fc    = (const float*)d_in[12];
  float* out = (float*)d_out;

  char* p = (char*)d_ws;
  auto take = [&](size_t n) { char* q = p; p += (n + 255) & ~(size_t)255; return q; };
  bf16* wih0b = (bf16*)take((size_t)3 * GRU_H * PADX * 2);
  bf16* whh0b = (bf16*)take((size_t)3 * GRU_H * GRU_H * 2);
  bf16* wih1b = (bf16*)take((size_t)3 * GRU_H * GRU_H * 2);
  bf16* whh1b = (bf16*)take((size_t)3 * GRU_H * GRU_H * 2);
  bf16* wfcb  = (bf16*)take((size_t)ODIM * GRU_H * 2);
  bf16* decb  = (bf16*)take((size_t)BATCH * PADX * 2);
  float* h0f[2], *h1f[2];
  bf16* h0b[2], *h1b[2];
  h0f[0] = (float*)take((size_t)BATCH * GRU_H * 4);
  h0f[1] = (float*)take((size_t)BATCH * GRU_H * 4);
  h1f[0] = (float*)take((size_t)BATCH * GRU_H * 4);
  h1f[1] = (float*)take((size_t)BATCH * GRU_H * 4);
  h0b[0] = (bf16*)take((size_t)BATCH * GRU_H * 2);
  h0b[1] = (bf16*)take((size_t)BATCH * GRU_H * 2);
  h1b[0] = (bf16*)take((size_t)BATCH * GRU_H * 2);
  h1b[1] = (bf16*)take((size_t)BATCH * GRU_H * 2);
  float* fcpart = (float*)take((size_t)16 * BATCH * ODIM * 4);

  // one-time (per launch) conversions
  k_cvt_pad<<<768, 256, 0, stream>>>(W_ih0, wih0b, 3 * GRU_H, ODIM, PADX);
  k_cvt<<<2048, 256, 0, stream>>>(W_hh0, whh0b, 3 * GRU_H * GRU_H);
  k_cvt<<<2048, 256, 0, stream>>>(W_ih1, wih1b, 3 * GRU_H * GRU_H);
  k_cvt<<<2048, 256, 0, stream>>>(W_hh1, whh1b, 3 * GRU_H * GRU_H);
  k_cvt<<<192, 256, 0, stream>>>(W_fc, wfcb, ODIM * GRU_H);
  k_cvt_pad<<<512, 256, 0, stream>>>(input, decb, BATCH, ODIM, PADX);
  k_init_h<<<2048, 256, 0, stream>>>(hiddens, h0f[0], h0b[0], BATCH * GRU_H);
  k_init_h<<<2048, 256, 0, stream>>>(hiddens + (size_t)BATCH * GRU_H, h1f[0], h1b[0], BATCH * GRU_H);

  int cur = 0;
  for (int t = 0; t < TSTEPS; ++t) {
    int nxt = cur ^ 1;
    k_gru<<<dim3(32, 16), 256, 0, stream>>>(decb, PADX, h0b[cur], wih0b, whh0b,
                                            b_ih0, b_hh0, h0f[cur], h0f[nxt], h0b[nxt]);
    k_gru<<<dim3(32, 16), 256, 0, stream>>>(h0b[nxt], GRU_H, h1b[cur], wih1b, whh1b,
                                            b_ih1, b_hh1, h1f[cur], h1f[nxt], h1b[nxt]);
    k_fc_part<<<dim3(16, 16), 256, 0, stream>>>(h1b[nxt], wfcb, fcpart);
    k_fc_red<<<384, 256, 0, stream>>>(fcpart, b_fc, out, decb, t);
    cur = nxt;
  }
}